// Round 9
// baseline (155.184 us; speedup 1.0000x reference)
//
#include <hip/hip_runtime.h>
#include <stdint.h>

typedef unsigned short u16;
typedef unsigned int   u32;
typedef unsigned long long u64;
typedef __attribute__((ext_vector_type(8)))  short short8;   // 8 x bf16 fragment
typedef __attribute__((ext_vector_type(4)))  float f32x4;
typedef __attribute__((ext_vector_type(16))) float f32x16;   // 32x32 MFMA accumulator
typedef __attribute__((ext_vector_type(4)))  unsigned int u32x4;

// ---------- helpers ----------
__device__ __forceinline__ u16 f2bf(float f) {          // RNE f32 -> bf16
  u32 u = __builtin_bit_cast(u32, f);
  u32 r = u + 0x7FFFu + ((u >> 16) & 1u);
  return (u16)(r >> 16);
}

__device__ __forceinline__ u32 cvtpk(float a, float b) { // 2xf32 -> packed bf16
  u32 r;
  asm("v_cvt_pk_bf16_f32 %0, %1, %2" : "=v"(r) : "v"(a), "v"(b));
  return r;
}

// async global->LDS, 16B per lane (dest must be wave-uniform base + lane*16)
__device__ __forceinline__ void gload_lds16(const void* g, void* l) {
  __builtin_amdgcn_global_load_lds(
      (__attribute__((address_space(1))) void*)(uintptr_t)g,
      (__attribute__((address_space(3))) void*)(u32)(uintptr_t)l,
      16, 0, 0);
}

#define SB() __builtin_amdgcn_sched_barrier(0)

// ---------- fused weight casts: grid.y selects which 512x512 matrix ----------
__global__ void cast4_kernel(const float* __restrict__ s0, const float* __restrict__ s1,
                             const float* __restrict__ s2, const float* __restrict__ s3,
                             u16* __restrict__ d0, u16* __restrict__ d1,
                             u16* __restrict__ d2, u16* __restrict__ d3, int n8) {
  const int sel = blockIdx.y;
  const float* src = sel == 0 ? s0 : sel == 1 ? s1 : sel == 2 ? s2 : s3;
  u16* dst = sel == 0 ? d0 : sel == 1 ? d1 : sel == 2 ? d2 : d3;
  int i = blockIdx.x * blockDim.x + threadIdx.x;
  if (i >= n8) return;
  const float4* s4 = (const float4*)src;
  float4 x = s4[2 * (size_t)i];
  float4 y = s4[2 * (size_t)i + 1];
  u32x4 r;
  r.x = cvtpk(x.x, x.y); r.y = cvtpk(x.z, x.w);
  r.z = cvtpk(y.x, y.y); r.w = cvtpk(y.z, y.w);
  *(u32x4*)(dst + 8 * (size_t)i) = r;
}

// ---------- pack {q_seq, c_bits} per position ----------
__global__ void pack_kernel(const int* __restrict__ q_seq, const int* __restrict__ c_seq,
                            int2* __restrict__ meta, int n) {
  int i = blockIdx.x * blockDim.x + threadIdx.x;
  if (i >= n) return;
  u32 bits = 0;
#pragma unroll
  for (int j = 0; j < 32; ++j)
    bits |= (c_seq[(size_t)i * 32 + j] != 0) ? (1u << j) : 0u;
  meta[i] = make_int2(q_seq[i], (int)bits);
}

// ---------- mask precompute: 2-bit m per (b, ktile32, q), tri included ----------
__global__ __launch_bounds__(256) void mask_kernel(const int2* __restrict__ meta,
                                                   u64* __restrict__ maskw) {
  const int qc = blockIdx.x, kt = blockIdx.y, b = blockIdx.z;
  const int t = threadIdx.x;
  const int q = qc * 256 + t;
  __shared__ int2 colm[32];
  if (t < 32) colm[t] = meta[b * 1024 + kt * 32 + t];
  __syncthreads();
  const int2 qm = meta[b * 1024 + q];
  const int rs = qm.x; const u32 rb = (u32)qm.y;
  u64 w = 0;
#pragma unroll
  for (int j = 0; j < 32; ++j) {
    const int2 cm = colm[j];
    const int kj = kt * 32 + j;
    u32 m = 0;
    if (kj < q) m = 1u + (rs == cm.x ? 1u : 0u) + (((rb & (u32)cm.y) != 0u) ? 1u : 0u);
    w |= (u64)m << (2 * j);
  }
  maskw[((size_t)b * 32 + kt) * 1024 + q] = w;
}

// ---------- QKV projection: 256x256 tile, 8 waves, 2-phase dbuf ----------
// Stacked M = 3x16384 (which = mb>>6 selects input+weight third). BK=64,
// K=512 -> 8 steps. Per step: issue A(t+1) f32 loads + B(t+1) gload_lds ->
// MFMA on buf (hides latency) -> vmcnt(4) -> cvt+ds_write A -> vmcnt(0) +
// ONE barrier. T2 swizzle (content via pre-swizzled source, linear dests).
// Per-wave output 128x64 (wm=w>>2, wn=w&3), acc[8][4].
//  which 0 (Q): out [b][h][s][64]
//  which 1 (K): tiled [b][h][s/32][d/8][s&31][d&7]
//  which 2 (V): tiled [b][h][s/8][d][s&7]
__global__ __launch_bounds__(512, 2) void gemm_qkv(const float* __restrict__ qf,
                                                   const float* __restrict__ kf,
                                                   const float* __restrict__ vf,
                                                   const u16* __restrict__ Wcat,
                                                   const float* __restrict__ bv,
                                                   const float* __restrict__ bk,
                                                   const float* __restrict__ bq,
                                                   u16* __restrict__ qhb,
                                                   u16* __restrict__ khb,
                                                   u16* __restrict__ vTb,
                                                   float kscale) {
  const int K = 512;
  __shared__ __align__(16) u16 As[2][256 * 64];
  __shared__ __align__(16) u16 Bs[2][256 * 64];
  const int t    = threadIdx.x;
  const int lane = t & 63;
  const int w    = t >> 6;                          // 0..7
  const int g    = lane >> 4, l15 = lane & 15;
  const int wm   = w >> 2, wn = w & 3;
  const int wrk  = (blockIdx.x & 7) * 48 + (blockIdx.x >> 3);  // XCD-chunked, 384 blocks
  const int mb   = wrk >> 1, nbi = wrk & 1;
  const int which = mb >> 6;                        // 0:q 1:k 2:v
  const float* Ax   = which == 0 ? qf : which == 1 ? kf : vf;
  const float* bias = which == 0 ? bv : which == 1 ? bk : bq;  // ref weight shuffle
  const float scale = which == 1 ? kscale : 1.0f;
  u16* outb = which == 0 ? qhb : which == 1 ? khb : vTb;
  const int mloc = (mb & 63) << 8;                  // row base within this input
  const int n0   = nbi << 8;                        // col base within this third
  const u16* W   = Wcat + (size_t)which * 512 * 512;

  const int srow = t >> 3;                          // 0..63
  const int scol = (((t & 7) ^ (srow & 7)) << 3);   // pre-swizzled source slot
  const int rsw  = l15 & 7;

  f32x4 acc[8][4];
#pragma unroll
  for (int i = 0; i < 8; ++i)
#pragma unroll
    for (int j = 0; j < 4; ++j) acc[i][j] = f32x4{0.f, 0.f, 0.f, 0.f};

  float4 ax[4], ay[4];

#define LOAD_A(kt)                                                            \
  {                                                                           \
    _Pragma("unroll")                                                         \
    for (int i = 0; i < 4; ++i) {                                             \
      const float* src = Ax + (size_t)(mloc + 64 * i + srow) * K + (kt) * 64 + scol; \
      ax[i] = *(const float4*)src;                                            \
      ay[i] = *(const float4*)(src + 4);                                      \
    }                                                                         \
  }
#define STAGE_B(kt, buf)                                                      \
  {                                                                           \
    _Pragma("unroll")                                                         \
    for (int i = 0; i < 4; ++i)                                               \
      gload_lds16(W + (size_t)(n0 + 64 * i + srow) * K + (kt) * 64 + scol,    \
                  &Bs[buf][i * 4096 + t * 8]);                                \
  }
#define WRITE_A(buf)                                                          \
  {                                                                           \
    _Pragma("unroll")                                                         \
    for (int i = 0; i < 4; ++i) {                                             \
      u32x4 r;                                                                \
      r.x = cvtpk(ax[i].x, ax[i].y); r.y = cvtpk(ax[i].z, ax[i].w);           \
      r.z = cvtpk(ay[i].x, ay[i].y); r.w = cvtpk(ay[i].z, ay[i].w);           \
      *(u32x4*)(&As[buf][i * 4096 + t * 8]) = r;                              \
    }                                                                         \
  }
#define COMPUTE(buf)                                                          \
  {                                                                           \
    _Pragma("unroll")                                                         \
    for (int kk = 0; kk < 2; ++kk) {                                          \
      short8 a[8], b[4];                                                      \
      _Pragma("unroll")                                                       \
      for (int mi = 0; mi < 8; ++mi)                                          \
        a[mi] = *(const short8*)(&As[buf][(wm * 128 + mi * 16 + l15) * 64     \
                                 + (((kk * 4 + g) ^ rsw) << 3)]);             \
      _Pragma("unroll")                                                       \
      for (int ni = 0; ni < 4; ++ni)                                          \
        b[ni] = *(const short8*)(&Bs[buf][(wn * 64 + ni * 16 + l15) * 64      \
                                 + (((kk * 4 + g) ^ rsw) << 3)]);             \
      _Pragma("unroll")                                                       \
      for (int mi = 0; mi < 8; ++mi)                                          \
        _Pragma("unroll")                                                     \
        for (int ni = 0; ni < 4; ++ni)                                        \
          acc[mi][ni] = __builtin_amdgcn_mfma_f32_16x16x32_bf16(a[mi], b[ni], acc[mi][ni], 0, 0, 0); \
    }                                                                         \
  }

  // prologue: fill buf 0
  LOAD_A(0); SB();
  STAGE_B(0, 0); SB();
  asm volatile("s_waitcnt vmcnt(4)" ::: "memory");   // A(0) regs ready
  WRITE_A(0); SB();
  asm volatile("s_waitcnt vmcnt(0) lgkmcnt(0)" ::: "memory");
  __builtin_amdgcn_s_barrier();
  SB();

  for (int tt = 0; tt < 7; ++tt) {
    const int cur = tt & 1, nxt = cur ^ 1;
    LOAD_A(tt + 1); SB();                            // 8 VMEM (oldest)
    STAGE_B(tt + 1, nxt); SB();                      // 4 VMEM->LDS (newest)
    COMPUTE(cur); SB();                              // hides the loads
    asm volatile("s_waitcnt vmcnt(4)" ::: "memory"); // A regs arrived
    WRITE_A(nxt); SB();
    asm volatile("s_waitcnt vmcnt(0) lgkmcnt(0)" ::: "memory");
    __builtin_amdgcn_s_barrier();
    SB();
  }
  COMPUTE(1);                                        // tt=7 lives in buf 1

#undef LOAD_A
#undef STAGE_B
#undef WRITE_A
#undef COMPUTE

#pragma unroll
  for (int ni = 0; ni < 4; ++ni) {
    const int col = n0 + wn * 64 + ni * 16 + l15;    // 0..511 within this third
    const float bz = bias[col];
#pragma unroll
    for (int mi = 0; mi < 8; ++mi) {
#pragma unroll
      for (int r = 0; r < 4; ++r) {
        const int row = mloc + wm * 128 + mi * 16 + g * 4 + r;
        const u16 val = f2bf((acc[mi][ni][r] + bz) * scale);
        const size_t base = ((size_t)(row >> 10) * 8 + (col >> 6)) * 65536;
        const int s = row & 1023, d = col & 63;
        if (which == 0) {
          outb[base + (size_t)s * 64 + d] = val;
        } else if (which == 1) {
          outb[base + (s >> 5) * 2048 + (d >> 3) * 256 + (s & 31) * 8 + (d & 7)] = val;
        } else {
          outb[base + (s >> 3) * 512 + d * 8 + (s & 7)] = val;
        }
      }
    }
  }
}

// ---------- final GEMM: 256x256 tile, 8 waves, 2-phase dbuf, pure bf16 ----
__global__ __launch_bounds__(512, 2) void gemm_out(const u16* __restrict__ A,
                                                   const u16* __restrict__ W,
                                                   const float* __restrict__ bias,
                                                   float* __restrict__ outp) {
  const int K = 512, N = 512;
  __shared__ __align__(16) u16 As[2][256 * 64];
  __shared__ __align__(16) u16 Bs[2][256 * 64];
  const int t    = threadIdx.x;
  const int lane = t & 63;
  const int w    = t >> 6;
  const int g    = lane >> 4, l15 = lane & 15;
  const int wm   = w >> 2, wn = w & 3;
  const int wrk  = (blockIdx.x & 7) * 16 + (blockIdx.x >> 3);  // 128 blocks
  const int mb   = wrk >> 1, nbi = wrk & 1;
  const int m0   = mb << 8, n0 = nbi << 8;
  const int srow = t >> 3;
  const int scol = (((t & 7) ^ (srow & 7)) << 3);
  const int rsw  = l15 & 7;

  f32x4 acc[8][4];
#pragma unroll
  for (int i = 0; i < 8; ++i)
#pragma unroll
    for (int j = 0; j < 4; ++j) acc[i][j] = f32x4{0.f, 0.f, 0.f, 0.f};

#define STAGE(kt, buf)                                                        \
  {                                                                           \
    _Pragma("unroll")                                                         \
    for (int i = 0; i < 4; ++i) {                                             \
      gload_lds16(A + (size_t)(m0 + 64 * i + srow) * K + (kt) * 64 + scol,    \
                  &As[buf][i * 4096 + t * 8]);                                \
      gload_lds16(W + (size_t)(n0 + 64 * i + srow) * K + (kt) * 64 + scol,    \
                  &Bs[buf][i * 4096 + t * 8]);                                \
    }                                                                         \
  }
#define COMPUTE(buf)                                                          \
  {                                                                           \
    _Pragma("unroll")                                                         \
    for (int kk = 0; kk < 2; ++kk) {                                          \
      short8 a[8], b[4];                                                      \
      _Pragma("unroll")                                                       \
      for (int mi = 0; mi < 8; ++mi)                                          \
        a[mi] = *(const short8*)(&As[buf][(wm * 128 + mi * 16 + l15) * 64     \
                                 + (((kk * 4 + g) ^ rsw) << 3)]);             \
      _Pragma("unroll")                                                       \
      for (int ni = 0; ni < 4; ++ni)                                          \
        b[ni] = *(const short8*)(&Bs[buf][(wn * 64 + ni * 16 + l15) * 64      \
                                 + (((kk * 4 + g) ^ rsw) << 3)]);             \
      _Pragma("unroll")                                                       \
      for (int mi = 0; mi < 8; ++mi)                                          \
        _Pragma("unroll")                                                     \
        for (int ni = 0; ni < 4; ++ni)                                        \
          acc[mi][ni] = __builtin_amdgcn_mfma_f32_16x16x32_bf16(a[mi], b[ni], acc[mi][ni], 0, 0, 0); \
    }                                                                         \
  }

  STAGE(0, 0); SB();
  asm volatile("s_waitcnt vmcnt(0)" ::: "memory");
  __builtin_amdgcn_s_barrier();
  SB();
  for (int tt = 0; tt < 7; ++tt) {
    const int cur = tt & 1, nxt = cur ^ 1;
    STAGE(tt + 1, nxt); SB();
    COMPUTE(cur); SB();
    asm volatile("s_waitcnt vmcnt(0)" ::: "memory");
    __builtin_amdgcn_s_barrier();
    SB();
  }
  COMPUTE(1);
#undef STAGE
#undef COMPUTE

#pragma unroll
  for (int ni = 0; ni < 4; ++ni) {
    const int col = n0 + wn * 64 + ni * 16 + l15;
    const float bz = bias[col];
#pragma unroll
    for (int mi = 0; mi < 8; ++mi)
#pragma unroll
      for (int r = 0; r < 4; ++r) {
        const int row = m0 + wm * 128 + mi * 16 + g * 4 + r;
        outp[(size_t)row * N + col] = acc[mi][ni][r] + bz;
      }
  }
}

// ---------- flash attention: wave-pair kv-split, swapped-QK 32x32 ----------
// (unchanged)
__global__ __launch_bounds__(256, 4) void attn_kernel(const u16* __restrict__ qh,
                                                      const u16* __restrict__ kh,
                                                      const u16* __restrict__ vT,
                                                      const u64* __restrict__ maskw,
                                                      u16* __restrict__ outc) {
  const int h  = blockIdx.x;
  const int qp = blockIdx.y;
  const int b  = blockIdx.z;
  const int lane = threadIdx.x & 63;
  const int wid  = threadIdx.x >> 6;
  const int pair = wid >> 1, p = wid & 1;
  const int l31 = lane & 31;
  const int hh  = lane >> 5;
  const int hh8 = hh << 3, fourh = hh << 2, eighth = hh << 3;
  const int jt = pair ? (31 - qp) : qp;
  const int q0 = jt << 5;
  const int qi = q0 + l31;
  const size_t bh = (size_t)b * 8 + h;
  const u16* Q  = qh + bh * 65536;
  const u16* Kp = kh + bh * 65536;
  const u16* Vt = vT + bh * 65536;
  const u64* mrow = maskw + (size_t)b * 32768 + qi;

  __shared__ float mO[2][32][64];
  __shared__ float mL[2][64];
  __shared__ __align__(16) float Sl[2][32];

  short8 qB[4];
#pragma unroll
  for (int i = 0; i < 4; ++i)
    qB[i] = *(const short8*)(Q + (size_t)qi * 64 + i * 16 + eighth);

  f32x16 O0, O1;
#pragma unroll
  for (int i = 0; i < 16; ++i) { O0[i] = 0.f; O1[i] = 0.f; }
  float lr[4] = {0.f, 0.f, 0.f, 0.f};

  const int nt = jt + 1;

  short8 kA[4];
#pragma unroll
  for (int i = 0; i < 4; ++i)
    kA[i] = *(const short8*)(Kp + p * 2048 + ((2 * i + hh) * 32 + l31) * 8);
  u64 wm = mrow[(size_t)p << 10];

  for (int t = p; t < nt; t += 2) {
    const int k0 = t << 5;

    f32x16 S;
#pragma unroll
    for (int i = 0; i < 16; ++i) S[i] = 0.f;
#pragma unroll
    for (int i = 0; i < 4; ++i)
      S = __builtin_amdgcn_mfma_f32_32x32x16_bf16(kA[i], qB[i], S, 0, 0, 0);

    u64 wmn = 0;
    if (t + 2 < nt) {
#pragma unroll
      for (int i = 0; i < 4; ++i)
        kA[i] = *(const short8*)(Kp + (t + 2) * 2048 + ((2 * i + hh) * 32 + l31) * 8);
      wmn = mrow[(size_t)(t + 2) << 10];
    }

    short8 vB[2][2];
#pragma unroll
    for (int t4 = 0; t4 < 2; ++t4)
#pragma unroll
      for (int j = 0; j < 2; ++j)
        vB[t4][j] = *(const short8*)(Vt + (size_t)(t * 4 + t4 * 2 + hh) * 512 + (32 * j + l31) * 8);

    const u32 wsh0 = ((u32)wm) >> hh8;
    const u32 wsh1 = ((u32)(wm >> 32)) >> hh8;
    u32 pk[8];
#pragma unroll
    for (int s = 0; s < 4; ++s) {
      const u32 wsel = (s < 2) ? wsh0 : wsh1;
      float pv[4];
#pragma unroll
      for (int r = 0; r < 4; ++r) {
        const int m = 4 * s + r;
        const u32 m2 = (wsel >> (2 * r + 16 * (s & 1))) & 3u;
        float e;
        asm("v_exp_f32 %0, %1" : "=v"(e) : "v"(S[m]));
        const float pp = (m2 != 0u) ? e : 0.f;
        lr[r] += pp;
        asm("v_ldexp_f32 %0, %1, %2" : "=v"(pv[r]) : "v"(pp), "v"(m2));
      }
      pk[2 * s]     = cvtpk(pv[0], pv[1]);
      pk[2 * s + 1] = cvtpk(pv[2], pv[3]);
    }
    wm = wmn;

#pragma unroll
    for (int t4 = 0; t4 < 2; ++t4) {
      u32 a0 = pk[4 * t4 + 0], b0 = pk[4 * t4 + 2];
      u32 a1 = pk[4 * t4 + 1], b1 = pk[4 * t4 + 3];
      asm("v_permlane32_swap_b32 %0, %1" : "+v"(a0), "+v"(b0));
      asm("v_permlane32_swap_b32 %0, %1" : "+v"(a1), "+v"(b1));
      u32x4 w; w.x = a0; w.y = a1; w.z = b0; w.w = b1;
      const short8 pa = __builtin_bit_cast(short8, w);
      O0 = __builtin_amdgcn_mfma_f32_32x32x16_bf16(pa, vB[t4][0], O0, 0, 0, 0);
      O1 = __builtin_amdgcn_mfma_f32_32x32x16_bf16(pa, vB[t4][1], O1, 0, 0, 0);
    }
  }

  float lrun = (lr[0] + lr[1]) + (lr[2] + lr[3]);

  if (p == 1) {
#pragma unroll
    for (int r = 0; r < 16; ++r) {
      mO[pair][r][lane]      = O0[r];
      mO[pair][16 + r][lane] = O1[r];
    }
    mL[pair][lane] = lrun;
  }
  __syncthreads();
  if (p == 0) {
#pragma unroll
    for (int r = 0; r < 16; ++r) {
      O0[r] += mO[pair][r][lane];
      O1[r] += mO[pair][16 + r][lane];
    }
    lrun += mL[pair][lane];

    const float ssum = lrun + __shfl_xor(lrun, 32);
    if (lane < 32) Sl[pair][l31] = (ssum > 0.f) ? 0.25f / ssum : 0.f;
    __builtin_amdgcn_sched_barrier(0);
    asm volatile("s_waitcnt lgkmcnt(0)" ::: "memory");
    __builtin_amdgcn_sched_barrier(0);
#pragma unroll
    for (int t2 = 0; t2 < 4; ++t2) {
      const float4 inv4 = *(const float4*)&Sl[pair][8 * t2 + fourh];
#pragma unroll
      for (int r = 0; r < 4; ++r) {
        const int m = 4 * t2 + r;
        const float iv = (r == 0) ? inv4.x : (r == 1) ? inv4.y : (r == 2) ? inv4.z : inv4.w;
        const int qrow = q0 + 8 * t2 + fourh + r;
        u16* op = outc + ((size_t)b * 1024 + qrow) * 512 + h * 64;
        op[l31]      = f2bf(O0[m] * iv);
        op[32 + l31] = f2bf(O1[m] * iv);
      }
    }
  }
}

// ---------- launch ----------
extern "C" void kernel_launch(void* const* d_in, const int* in_sizes, int n_in,
                              void* d_out, int out_size, void* d_ws, size_t ws_size,
                              hipStream_t stream) {
  (void)in_sizes; (void)n_in; (void)out_size; (void)ws_size;
  const float* q    = (const float*)d_in[0];
  const float* k    = (const float*)d_in[1];
  const float* v    = (const float*)d_in[2];
  const int*  q_seq = (const int*)d_in[3];
  const int*  c_seq = (const int*)d_in[4];
  const float* Wq   = (const float*)d_in[5];
  const float* bq   = (const float*)d_in[6];
  const float* Wk   = (const float*)d_in[7];
  const float* bk   = (const float*)d_in[8];
  const float* Wv   = (const float*)d_in[9];
  const float* bv   = (const float*)d_in[10];
  const float* Wo   = (const float*)d_in[11];
  const float* bo   = (const float*)d_in[12];
  float* out = (float*)d_out;

  char* ws = (char*)d_ws;
  const size_t SZH = 16ull * 8 * 1024 * 64 * 2;   // 16.78 MB per [B][H][...] bf16
  u16* qhb   = (u16*)(ws + 0 * SZH);
  u16* khb   = (u16*)(ws + 1 * SZH);
  u16* vTb   = (u16*)(ws + 2 * SZH);
  u16* attnc = (u16*)(ws + 3 * SZH);
  u16* Wvb = (u16*)(ws + 4 * SZH + 0 * 524288);   // Wcat = [Wv|Wk|Wq] contiguous
  u16* Wkb = (u16*)(ws + 4 * SZH + 1 * 524288);
  u16* Wqb = (u16*)(ws + 4 * SZH + 2 * 524288);
  u16* Wob = (u16*)(ws + 4 * SZH + 3 * 524288);
  int2* meta  = (int2*)(ws + 4 * SZH + 4 * 524288);
  u64* maskw  = (u64*)(ws + 4 * SZH + 4 * 524288 + 131072);

  const int n8w = 512 * 512 / 8;
  cast4_kernel<<<dim3(n8w / 256, 4), 256, 0, stream>>>(Wv, Wk, Wq, Wo,
                                                       Wvb, Wkb, Wqb, Wob, n8w);
  pack_kernel<<<64, 256, 0, stream>>>(q_seq, c_seq, meta, 16384);
  mask_kernel<<<dim3(4, 32, 16), 256, 0, stream>>>(meta, maskw);

  const float KSCALE = 0.18033688011112042f;   // log2(e)/8 -> softmax exp is 2^s
  gemm_qkv<<<dim3(384), 512, 0, stream>>>(q, k, v, Wvb, bv, bk, bq,
                                          qhb, khb, vTb, KSCALE);
  attn_kernel<<<dim3(8, 16, 16), 256, 0, stream>>>(qhb, khb, vTb, maskw, attnc);
  gemm_out<<<dim3(128), 512, 0, stream>>>(attnc, Wob, bo, out);
}

// Round 10
// 144.417 us; speedup vs baseline: 1.0746x; 1.0746x over previous
//
#include <hip/hip_runtime.h>
#include <stdint.h>

typedef unsigned short u16;
typedef unsigned int   u32;
typedef unsigned long long u64;
typedef __attribute__((ext_vector_type(8)))  short short8;   // 8 x bf16 fragment
typedef __attribute__((ext_vector_type(4)))  float f32x4;
typedef __attribute__((ext_vector_type(16))) float f32x16;   // 32x32 MFMA accumulator
typedef __attribute__((ext_vector_type(4)))  unsigned int u32x4;

// ---------- helpers ----------
__device__ __forceinline__ u16 f2bf(float f) {          // RNE f32 -> bf16
  u32 u = __builtin_bit_cast(u32, f);
  u32 r = u + 0x7FFFu + ((u >> 16) & 1u);
  return (u16)(r >> 16);
}

__device__ __forceinline__ u32 cvtpk(float a, float b) { // 2xf32 -> packed bf16
  u32 r;
  asm("v_cvt_pk_bf16_f32 %0, %1, %2" : "=v"(r) : "v"(a), "v"(b));
  return r;
}

// async global->LDS, 16B per lane (dest must be wave-uniform base + lane*16)
__device__ __forceinline__ void gload_lds16(const void* g, void* l) {
  __builtin_amdgcn_global_load_lds(
      (__attribute__((address_space(1))) void*)(uintptr_t)g,
      (__attribute__((address_space(3))) void*)(u32)(uintptr_t)l,
      16, 0, 0);
}

#define SB() __builtin_amdgcn_sched_barrier(0)

// ---------- fused weight casts: grid.y selects which 512x512 matrix ----------
__global__ void cast4_kernel(const float* __restrict__ s0, const float* __restrict__ s1,
                             const float* __restrict__ s2, const float* __restrict__ s3,
                             u16* __restrict__ d0, u16* __restrict__ d1,
                             u16* __restrict__ d2, u16* __restrict__ d3, int n8) {
  const int sel = blockIdx.y;
  const float* src = sel == 0 ? s0 : sel == 1 ? s1 : sel == 2 ? s2 : s3;
  u16* dst = sel == 0 ? d0 : sel == 1 ? d1 : sel == 2 ? d2 : d3;
  int i = blockIdx.x * blockDim.x + threadIdx.x;
  if (i >= n8) return;
  const float4* s4 = (const float4*)src;
  float4 x = s4[2 * (size_t)i];
  float4 y = s4[2 * (size_t)i + 1];
  u32x4 r;
  r.x = cvtpk(x.x, x.y); r.y = cvtpk(x.z, x.w);
  r.z = cvtpk(y.x, y.y); r.w = cvtpk(y.z, y.w);
  *(u32x4*)(dst + 8 * (size_t)i) = r;
}

// ---------- pack {q_seq, c_bits} per position ----------
__global__ void pack_kernel(const int* __restrict__ q_seq, const int* __restrict__ c_seq,
                            int2* __restrict__ meta, int n) {
  int i = blockIdx.x * blockDim.x + threadIdx.x;
  if (i >= n) return;
  u32 bits = 0;
#pragma unroll
  for (int j = 0; j < 32; ++j)
    bits |= (c_seq[(size_t)i * 32 + j] != 0) ? (1u << j) : 0u;
  meta[i] = make_int2(q_seq[i], (int)bits);
}

// ---------- mask precompute: 2-bit m per (b, ktile32, q), tri included ----------
__global__ __launch_bounds__(256) void mask_kernel(const int2* __restrict__ meta,
                                                   u64* __restrict__ maskw) {
  const int qc = blockIdx.x, kt = blockIdx.y, b = blockIdx.z;
  const int t = threadIdx.x;
  const int q = qc * 256 + t;
  __shared__ int2 colm[32];
  if (t < 32) colm[t] = meta[b * 1024 + kt * 32 + t];
  __syncthreads();
  const int2 qm = meta[b * 1024 + q];
  const int rs = qm.x; const u32 rb = (u32)qm.y;
  u64 w = 0;
#pragma unroll
  for (int j = 0; j < 32; ++j) {
    const int2 cm = colm[j];
    const int kj = kt * 32 + j;
    u32 m = 0;
    if (kj < q) m = 1u + (rs == cm.x ? 1u : 0u) + (((rb & (u32)cm.y) != 0u) ? 1u : 0u);
    w |= (u64)m << (2 * j);
  }
  maskw[((size_t)b * 32 + kt) * 1024 + q] = w;
}

// ---------- QKV projection: 128x128 tile, counted-vmcnt pipeline ----------
// Stacked M (which = mb>>7 selects input/weight/bias/output). As single-buffer
// (A restaged via reg-cvt each iter), Bs double-buffered. Per iter NO wait
// targets a same-iter load: vmcnt(4) gates A-regs (issued last iter),
// vmcnt(12) gates B(tt) (issued last iter); 12 loads fly across the barrier.
//  which 0 (Q): out [b][h][s][64]
//  which 1 (K): tiled [b][h][s/32][d/8][s&31][d&7]
//  which 2 (V): tiled [b][h][s/8][d][s&7]
__global__ __launch_bounds__(256) void gemm_qkv(const float* __restrict__ qf,
                                                const float* __restrict__ kf,
                                                const float* __restrict__ vf,
                                                const u16* __restrict__ Wcat,
                                                const float* __restrict__ bv,
                                                const float* __restrict__ bk,
                                                const float* __restrict__ bq,
                                                u16* __restrict__ qhb,
                                                u16* __restrict__ khb,
                                                u16* __restrict__ vTb,
                                                float kscale) {
  const int K = 512;
  __shared__ __align__(16) u16 As[128 * 64];
  __shared__ __align__(16) u16 Bs[2][128 * 64];
  const int t    = threadIdx.x;
  const int lane = t & 63;
  const int wid  = t >> 6;
  const int g    = lane >> 4, l15 = lane & 15;
  const int wm   = wid >> 1, wn = wid & 1;
  const int wrk  = (blockIdx.x & 7) * 192 + (blockIdx.x >> 3);  // XCD-chunked
  const int mb   = wrk >> 2, nbi = wrk & 3;
  const int which = mb >> 7;                        // 0:q 1:k 2:v
  const float* Ax   = which == 0 ? qf : which == 1 ? kf : vf;
  const float* bias = which == 0 ? bv : which == 1 ? bk : bq;  // ref weight shuffle
  const float scale = which == 1 ? kscale : 1.0f;
  u16* outb = which == 0 ? qhb : which == 1 ? khb : vTb;
  const int mloc = (mb & 127) << 7;                 // row base within this input
  const int n0   = nbi << 7;                        // col base within this third
  const u16* W   = Wcat + (size_t)which * 512 * 512;

  const int srow = t >> 3;
  const int scol = (((t & 7) ^ (srow & 7)) << 3);   // pre-swizzled source slot
  const int dcol = ((t & 7) << 3);                  // linear LDS dest slot
  const int rsw  = l15 & 7;

  f32x4 acc[4][4];
#pragma unroll
  for (int i = 0; i < 4; ++i)
#pragma unroll
    for (int j = 0; j < 4; ++j) acc[i][j] = f32x4{0.f, 0.f, 0.f, 0.f};

  float4 ax[4], ay[4];

#define LOAD_A(kt)                                                            \
  {                                                                           \
    _Pragma("unroll")                                                         \
    for (int i = 0; i < 4; ++i) {                                             \
      const float* src = Ax + (size_t)(mloc + 32 * i + srow) * K + (kt) * 64 + scol; \
      ax[i] = *(const float4*)src;                                            \
      ay[i] = *(const float4*)(src + 4);                                      \
    }                                                                         \
  }
#define STAGE_B(kt, buf)                                                      \
  {                                                                           \
    _Pragma("unroll")                                                         \
    for (int i = 0; i < 4; ++i)                                               \
      gload_lds16(W + (size_t)(n0 + i * 32 + srow) * K + (kt) * 64 + scol,    \
                  &Bs[buf][i * 2048 + t * 8]);                                \
  }
#define WRITE_A()                                                             \
  {                                                                           \
    _Pragma("unroll")                                                         \
    for (int i = 0; i < 4; ++i) {                                             \
      u32x4 r;                                                                \
      r.x = cvtpk(ax[i].x, ax[i].y); r.y = cvtpk(ax[i].z, ax[i].w);           \
      r.z = cvtpk(ay[i].x, ay[i].y); r.w = cvtpk(ay[i].z, ay[i].w);           \
      *(u32x4*)(&As[(32 * i + srow) * 64 + dcol]) = r;                        \
    }                                                                         \
  }
#define COMPUTE(buf)                                                          \
  {                                                                           \
    _Pragma("unroll")                                                         \
    for (int kk = 0; kk < 2; ++kk) {                                          \
      short8 a[4], b[4];                                                      \
      _Pragma("unroll")                                                       \
      for (int mi = 0; mi < 4; ++mi)                                          \
        a[mi] = *(const short8*)(&As[(wm * 64 + mi * 16 + l15) * 64           \
                                 + (((kk * 4 + g) ^ rsw) << 3)]);             \
      _Pragma("unroll")                                                       \
      for (int ni = 0; ni < 4; ++ni)                                          \
        b[ni] = *(const short8*)(&Bs[buf][(wn * 64 + ni * 16 + l15) * 64      \
                                 + (((kk * 4 + g) ^ rsw) << 3)]);             \
      _Pragma("unroll")                                                       \
      for (int mi = 0; mi < 4; ++mi)                                          \
        _Pragma("unroll")                                                     \
        for (int ni = 0; ni < 4; ++ni)                                        \
          acc[mi][ni] = __builtin_amdgcn_mfma_f32_16x16x32_bf16(a[mi], b[ni], acc[mi][ni], 0, 0, 0); \
    }                                                                         \
  }

  // prologue: issue A(0) (8 vmem, oldest) + B(0) (4 vmem)
  LOAD_A(0); SB();
  STAGE_B(0, 0); SB();

  for (int tt = 0; tt < 8; ++tt) {
    const int cur = tt & 1, nxt = cur ^ 1;
    // gate A(tt) regs: outstanding = A(tt)8 + B(tt)4 -> vmcnt(4) drains A only
    asm volatile("s_waitcnt vmcnt(4)" ::: "memory");
    SB();
    WRITE_A();                                  // cvt + ds_write into As
    SB();
    const int kn = (tt + 1) & 7;                // wrap keeps counts invariant
    LOAD_A(kn); SB();                           // 8 vmem
    STAGE_B(kn, nxt); SB();                     // 4 vmem
    // gate B(tt): outstanding = B(tt)4 + A(tt+1)8 + B(tt+1)4 = 16 -> vmcnt(12)
    asm volatile("s_waitcnt vmcnt(12) lgkmcnt(0)" ::: "memory");
    __builtin_amdgcn_s_barrier();               // As + Bs[cur] ready cross-wave
    SB();
    COMPUTE(cur);
    SB();
    __builtin_amdgcn_s_barrier();               // all reads done before next WRITE_A
    SB();
  }
  asm volatile("s_waitcnt vmcnt(0)" ::: "memory");   // drain dead wrap loads

#undef LOAD_A
#undef STAGE_B
#undef WRITE_A
#undef COMPUTE

#pragma unroll
  for (int ni = 0; ni < 4; ++ni) {
    const int col = n0 + wn * 64 + ni * 16 + l15;    // 0..511 within this third
    const float bz = bias[col];
#pragma unroll
    for (int mi = 0; mi < 4; ++mi) {
#pragma unroll
      for (int r = 0; r < 4; ++r) {
        const int row = mloc + wm * 64 + mi * 16 + g * 4 + r;
        const u16 val = f2bf((acc[mi][ni][r] + bz) * scale);
        const size_t base = ((size_t)(row >> 10) * 8 + (col >> 6)) * 65536;
        const int s = row & 1023, d = col & 63;
        if (which == 0) {
          outb[base + (size_t)s * 64 + d] = val;
        } else if (which == 1) {
          outb[base + (s >> 5) * 2048 + (d >> 3) * 256 + (s & 31) * 8 + (d & 7)] = val;
        } else {
          outb[base + (s >> 3) * 512 + d * 8 + (s & 7)] = val;
        }
      }
    }
  }
}

// ---------- final GEMM: 128x128, dbuf both, counted-vmcnt pipeline ----------
__global__ __launch_bounds__(256) void gemm_out(const u16* __restrict__ A,
                                                const u16* __restrict__ W,
                                                const float* __restrict__ bias,
                                                float* __restrict__ outp) {
  const int K = 512, N = 512;
  __shared__ __align__(16) u16 As[2][128 * 64];
  __shared__ __align__(16) u16 Bs[2][128 * 64];
  const int t    = threadIdx.x;
  const int lane = t & 63;
  const int wid  = t >> 6;
  const int g    = lane >> 4, l15 = lane & 15;
  const int wm   = wid >> 1, wn = wid & 1;
  const int wrk  = (blockIdx.x & 7) * 64 + (blockIdx.x >> 3);  // XCD-chunked
  const int mb   = wrk >> 2, nbi = wrk & 3;
  const int m0   = mb << 7, n0 = nbi << 7;
  const int srow = t >> 3;
  const int scol = (((t & 7) ^ (srow & 7)) << 3);
  const int rsw  = l15 & 7;

  f32x4 acc[4][4];
#pragma unroll
  for (int i = 0; i < 4; ++i)
#pragma unroll
    for (int j = 0; j < 4; ++j) acc[i][j] = f32x4{0.f, 0.f, 0.f, 0.f};

#define STAGE(kt, buf)                                                        \
  {                                                                           \
    _Pragma("unroll")                                                         \
    for (int i = 0; i < 4; ++i) {                                             \
      gload_lds16(A + (size_t)(m0 + i * 32 + srow) * K + (kt) * 64 + scol,    \
                  &As[buf][i * 2048 + t * 8]);                                \
      gload_lds16(W + (size_t)(n0 + i * 32 + srow) * K + (kt) * 64 + scol,    \
                  &Bs[buf][i * 2048 + t * 8]);                                \
    }                                                                         \
  }
#define COMPUTE(buf)                                                          \
  {                                                                           \
    _Pragma("unroll")                                                         \
    for (int kk = 0; kk < 2; ++kk) {                                          \
      short8 a[4], b[4];                                                      \
      _Pragma("unroll")                                                       \
      for (int mi = 0; mi < 4; ++mi)                                          \
        a[mi] = *(const short8*)(&As[buf][(wm * 64 + mi * 16 + l15) * 64      \
                                 + (((kk * 4 + g) ^ rsw) << 3)]);             \
      _Pragma("unroll")                                                       \
      for (int ni = 0; ni < 4; ++ni)                                          \
        b[ni] = *(const short8*)(&Bs[buf][(wn * 64 + ni * 16 + l15) * 64      \
                                 + (((kk * 4 + g) ^ rsw) << 3)]);             \
      _Pragma("unroll")                                                       \
      for (int mi = 0; mi < 4; ++mi)                                          \
        _Pragma("unroll")                                                     \
        for (int ni = 0; ni < 4; ++ni)                                        \
          acc[mi][ni] = __builtin_amdgcn_mfma_f32_16x16x32_bf16(a[mi], b[ni], acc[mi][ni], 0, 0, 0); \
    }                                                                         \
  }

  STAGE(0, 0); SB();                              // prologue: 8 vmem
  for (int tt = 0; tt < 8; ++tt) {
    const int cur = tt & 1, nxt = cur ^ 1;
    STAGE((tt + 1) & 7, nxt); SB();               // 8 vmem (wrap-dead on tt=7)
    // gate STAGE(tt): outstanding 16 -> vmcnt(8); tt>=1 covered by prev compute
    asm volatile("s_waitcnt vmcnt(8)" ::: "memory");
    __builtin_amdgcn_s_barrier();
    SB();
    COMPUTE(cur);
    SB();
    __builtin_amdgcn_s_barrier();                 // reads done before overwrite
    SB();
  }
  asm volatile("s_waitcnt vmcnt(0)" ::: "memory");
#undef STAGE
#undef COMPUTE

#pragma unroll
  for (int ni = 0; ni < 4; ++ni) {
    const int col = n0 + wn * 64 + ni * 16 + l15;
    const float bz = bias[col];
#pragma unroll
    for (int mi = 0; mi < 4; ++mi)
#pragma unroll
      for (int r = 0; r < 4; ++r) {
        const int row = m0 + wm * 64 + mi * 16 + g * 4 + r;
        outp[(size_t)row * N + col] = acc[mi][ni][r] + bz;
      }
  }
}

// ---------- flash attention: wave-pair kv-split, swapped-QK 32x32 ----------
// (unchanged)
__global__ __launch_bounds__(256, 4) void attn_kernel(const u16* __restrict__ qh,
                                                      const u16* __restrict__ kh,
                                                      const u16* __restrict__ vT,
                                                      const u64* __restrict__ maskw,
                                                      u16* __restrict__ outc) {
  const int h  = blockIdx.x;
  const int qp = blockIdx.y;
  const int b  = blockIdx.z;
  const int lane = threadIdx.x & 63;
  const int wid  = threadIdx.x >> 6;
  const int pair = wid >> 1, p = wid & 1;
  const int l31 = lane & 31;
  const int hh  = lane >> 5;
  const int hh8 = hh << 3, fourh = hh << 2, eighth = hh << 3;
  const int jt = pair ? (31 - qp) : qp;
  const int q0 = jt << 5;
  const int qi = q0 + l31;
  const size_t bh = (size_t)b * 8 + h;
  const u16* Q  = qh + bh * 65536;
  const u16* Kp = kh + bh * 65536;
  const u16* Vt = vT + bh * 65536;
  const u64* mrow = maskw + (size_t)b * 32768 + qi;

  __shared__ float mO[2][32][64];
  __shared__ float mL[2][64];
  __shared__ __align__(16) float Sl[2][32];

  short8 qB[4];
#pragma unroll
  for (int i = 0; i < 4; ++i)
    qB[i] = *(const short8*)(Q + (size_t)qi * 64 + i * 16 + eighth);

  f32x16 O0, O1;
#pragma unroll
  for (int i = 0; i < 16; ++i) { O0[i] = 0.f; O1[i] = 0.f; }
  float lr[4] = {0.f, 0.f, 0.f, 0.f};

  const int nt = jt + 1;

  short8 kA[4];
#pragma unroll
  for (int i = 0; i < 4; ++i)
    kA[i] = *(const short8*)(Kp + p * 2048 + ((2 * i + hh) * 32 + l31) * 8);
  u64 wm = mrow[(size_t)p << 10];

  for (int t = p; t < nt; t += 2) {
    const int k0 = t << 5;

    f32x16 S;
#pragma unroll
    for (int i = 0; i < 16; ++i) S[i] = 0.f;
#pragma unroll
    for (int i = 0; i < 4; ++i)
      S = __builtin_amdgcn_mfma_f32_32x32x16_bf16(kA[i], qB[i], S, 0, 0, 0);

    u64 wmn = 0;
    if (t + 2 < nt) {
#pragma unroll
      for (int i = 0; i < 4; ++i)
        kA[i] = *(const short8*)(Kp + (t + 2) * 2048 + ((2 * i + hh) * 32 + l31) * 8);
      wmn = mrow[(size_t)(t + 2) << 10];
    }

    short8 vB[2][2];
#pragma unroll
    for (int t4 = 0; t4 < 2; ++t4)
#pragma unroll
      for (int j = 0; j < 2; ++j)
        vB[t4][j] = *(const short8*)(Vt + (size_t)(t * 4 + t4 * 2 + hh) * 512 + (32 * j + l31) * 8);

    const u32 wsh0 = ((u32)wm) >> hh8;
    const u32 wsh1 = ((u32)(wm >> 32)) >> hh8;
    u32 pk[8];
#pragma unroll
    for (int s = 0; s < 4; ++s) {
      const u32 wsel = (s < 2) ? wsh0 : wsh1;
      float pv[4];
#pragma unroll
      for (int r = 0; r < 4; ++r) {
        const int m = 4 * s + r;
        const u32 m2 = (wsel >> (2 * r + 16 * (s & 1))) & 3u;
        float e;
        asm("v_exp_f32 %0, %1" : "=v"(e) : "v"(S[m]));
        const float pp = (m2 != 0u) ? e : 0.f;
        lr[r] += pp;
        asm("v_ldexp_f32 %0, %1, %2" : "=v"(pv[r]) : "v"(pp), "v"(m2));
      }
      pk[2 * s]     = cvtpk(pv[0], pv[1]);
      pk[2 * s + 1] = cvtpk(pv[2], pv[3]);
    }
    wm = wmn;

#pragma unroll
    for (int t4 = 0; t4 < 2; ++t4) {
      u32 a0 = pk[4 * t4 + 0], b0 = pk[4 * t4 + 2];
      u32 a1 = pk[4 * t4 + 1], b1 = pk[4 * t4 + 3];
      asm("v_permlane32_swap_b32 %0, %1" : "+v"(a0), "+v"(b0));
      asm("v_permlane32_swap_b32 %0, %1" : "+v"(a1), "+v"(b1));
      u32x4 w; w.x = a0; w.y = a1; w.z = b0; w.w = b1;
      const short8 pa = __builtin_bit_cast(short8, w);
      O0 = __builtin_amdgcn_mfma_f32_32x32x16_bf16(pa, vB[t4][0], O0, 0, 0, 0);
      O1 = __builtin_amdgcn_mfma_f32_32x32x16_bf16(pa, vB[t4][1], O1, 0, 0, 0);
    }
  }

  float lrun = (lr[0] + lr[1]) + (lr[2] + lr[3]);

  if (p == 1) {
#pragma unroll
    for (int r = 0; r < 16; ++r) {
      mO[pair][r][lane]      = O0[r];
      mO[pair][16 + r][lane] = O1[r];
    }
    mL[pair][lane] = lrun;
  }
  __syncthreads();
  if (p == 0) {
#pragma unroll
    for (int r = 0; r < 16; ++r) {
      O0[r] += mO[pair][r][lane];
      O1[r] += mO[pair][16 + r][lane];
    }
    lrun += mL[pair][lane];

    const float ssum = lrun + __shfl_xor(lrun, 32);
    if (lane < 32) Sl[pair][l31] = (ssum > 0.f) ? 0.25f / ssum : 0.f;
    __builtin_amdgcn_sched_barrier(0);
    asm volatile("s_waitcnt lgkmcnt(0)" ::: "memory");
    __builtin_amdgcn_sched_barrier(0);
#pragma unroll
    for (int t2 = 0; t2 < 4; ++t2) {
      const float4 inv4 = *(const float4*)&Sl[pair][8 * t2 + fourh];
#pragma unroll
      for (int r = 0; r < 4; ++r) {
        const int m = 4 * t2 + r;
        const float iv = (r == 0) ? inv4.x : (r == 1) ? inv4.y : (r == 2) ? inv4.z : inv4.w;
        const int qrow = q0 + 8 * t2 + fourh + r;
        u16* op = outc + ((size_t)b * 1024 + qrow) * 512 + h * 64;
        op[l31]      = f2bf(O0[m] * iv);
        op[32 + l31] = f2bf(O1[m] * iv);
      }
    }
  }
}

// ---------- launch ----------
extern "C" void kernel_launch(void* const* d_in, const int* in_sizes, int n_in,
                              void* d_out, int out_size, void* d_ws, size_t ws_size,
                              hipStream_t stream) {
  (void)in_sizes; (void)n_in; (void)out_size; (void)ws_size;
  const float* q    = (const float*)d_in[0];
  const float* k    = (const float*)d_in[1];
  const float* v    = (const float*)d_in[2];
  const int*  q_seq = (const int*)d_in[3];
  const int*  c_seq = (const int*)d_in[4];
  const float* Wq   = (const float*)d_in[5];
  const float* bq   = (const float*)d_in[6];
  const float* Wk   = (const float*)d_in[7];
  const float* bk   = (const float*)d_in[8];
  const float* Wv   = (const float*)d_in[9];
  const float* bv   = (const float*)d_in[10];
  const float* Wo   = (const float*)d_in[11];
  const float* bo   = (const float*)d_in[12];
  float* out = (float*)d_out;

  char* ws = (char*)d_ws;
  const size_t SZH = 16ull * 8 * 1024 * 64 * 2;   // 16.78 MB per [B][H][...] bf16
  u16* qhb   = (u16*)(ws + 0 * SZH);
  u16* khb   = (u16*)(ws + 1 * SZH);
  u16* vTb   = (u16*)(ws + 2 * SZH);
  u16* attnc = (u16*)(ws + 3 * SZH);
  u16* Wvb = (u16*)(ws + 4 * SZH + 0 * 524288);   // Wcat = [Wv|Wk|Wq] contiguous
  u16* Wkb = (u16*)(ws + 4 * SZH + 1 * 524288);
  u16* Wqb = (u16*)(ws + 4 * SZH + 2 * 524288);
  u16* Wob = (u16*)(ws + 4 * SZH + 3 * 524288);
  int2* meta  = (int2*)(ws + 4 * SZH + 4 * 524288);
  u64* maskw  = (u64*)(ws + 4 * SZH + 4 * 524288 + 131072);

  const int n8w = 512 * 512 / 8;
  cast4_kernel<<<dim3(n8w / 256, 4), 256, 0, stream>>>(Wv, Wk, Wq, Wo,
                                                       Wvb, Wkb, Wqb, Wob, n8w);
  pack_kernel<<<64, 256, 0, stream>>>(q_seq, c_seq, meta, 16384);
  mask_kernel<<<dim3(4, 32, 16), 256, 0, stream>>>(meta, maskw);

  const float KSCALE = 0.18033688011112042f;   // log2(e)/8 -> softmax exp is 2^s
  gemm_qkv<<<dim3(1536), 256, 0, stream>>>(q, k, v, Wvb, bv, bk, bq,
                                           qhb, khb, vTb, KSCALE);
  attn_kernel<<<dim3(8, 16, 16), 256, 0, stream>>>(qhb, khb, vTb, maskw, attnc);
  gemm_out<<<512, 256, 0, stream>>>(attnc, Wob, bo, out);
}